// Round 1
// baseline (8373.939 us; speedup 1.0000x reference)
//
#include <hip/hip_runtime.h>
#include <hip/hip_fp16.h>

// Problem constants
#define B_   2048
#define T_   512
#define H_   128
#define G_   512   // 4*H gates
#define R_   8     // batch rows per block
#define C_   8     // time-chunk steps
#define NTHR 512
#define WROW 65    // half2 stride per gate row (130 f16 = 128 + 2 pad -> bank-safe)

typedef _Float16 f16;
typedef _Float16 f16x2 __attribute__((ext_vector_type(2)));

// LDS layout (bytes)
#define OFF_W     0
#define SZ_W      (G_*WROW*4)          // 133120
#define OFF_H1C   (OFF_W + SZ_W)       // 133120
#define SZ_H1C    (C_*R_*H_*2)         // 16384
#define OFF_HA    (OFF_H1C + SZ_H1C)   // 149504
#define SZ_H      (R_*H_*2)            // 2048
#define OFF_HB    (OFF_HA + SZ_H)      // 151552
#define OFF_B0    (OFF_HB + SZ_H)      // 153600
#define OFF_BP    (OFF_B0 + G_*4)      // 155648
#define OFF_WIH0  (OFF_BP + G_*4)      // 157696
#define LDS_BYTES (OFF_WIH0 + G_*3*2)  // 160768 <= 160 KiB

__device__ __forceinline__ float fdot2_(f16x2 a, f16x2 b, float c) {
#if __has_builtin(__builtin_amdgcn_fdot2)
  return __builtin_amdgcn_fdot2(a, b, c, false);
#else
  return c + (float)a.x*(float)b.x + (float)a.y*(float)b.y;
#endif
}

__device__ __forceinline__ float sig_(float v)  { return 1.0f/(1.0f + __expf(-v)); }
__device__ __forceinline__ float tanh_(float v) { return 1.0f - 2.0f/(__expf(2.0f*v) + 1.0f); }

// Stage one 512x128 fp32 weight matrix from global into LDS as fp16 (padded rows).
__device__ __forceinline__ void stage_W(f16x2* __restrict__ W2,
                                        const float* __restrict__ gw, int tid) {
  const float2* src = (const float2*)gw;
  #pragma unroll 4
  for (int idx = tid; idx < G_*64; idx += NTHR) {
    const int g = idx >> 6, p = idx & 63;
    const float2 v = src[idx];
    f16x2 hv; hv.x = (f16)v.x; hv.y = (f16)v.y;
    W2[g*WROW + p] = hv;
  }
}

__global__ __launch_bounds__(NTHR, 1)
void lstm_fused(const float* __restrict__ x,
                const float* __restrict__ w_ih0, const float* __restrict__ w_hh0,
                const float* __restrict__ b_ih0, const float* __restrict__ b_hh0,
                const float* __restrict__ w_ih1, const float* __restrict__ w_hh1,
                const float* __restrict__ b_ih1, const float* __restrict__ b_hh1,
                const float* __restrict__ fc_w, const float* __restrict__ fc_b,
                float* __restrict__ out, float* __restrict__ ws)
{
  extern __shared__ char lds[];
  f16x2* W2    = (f16x2*)(lds + OFF_W);
  f16*   h1c   = (f16*)(lds + OFF_H1C);
  f16x2* h1c2  = (f16x2*)(lds + OFF_H1C);
  f16*   hA    = (f16*)(lds + OFF_HA);
  f16x2* hA2   = (f16x2*)(lds + OFF_HA);
  f16*   hB    = (f16*)(lds + OFF_HB);
  f16x2* hB2   = (f16x2*)(lds + OFF_HB);
  float* bias0 = (float*)(lds + OFF_B0);
  float* biasP = (float*)(lds + OFF_BP);
  f16*   wih0l = (f16*)(lds + OFF_WIH0);

  const int tid = (int)threadIdx.x;
  const int j   = tid & (H_-1);   // hidden unit
  const int s   = tid >> 7;       // row-slot 0..3
  const int blk = (int)blockIdx.x;
  float* __restrict__ xp = (float*)ws + (size_t)blk * (C_*R_*G_);

  // one-time staging of small constants
  if (tid < G_) {
    bias0[tid] = b_ih0[tid] + b_hh0[tid];
    biasP[tid] = b_ih1[tid] + b_hh1[tid];
    wih0l[tid*3+0] = (f16)w_ih0[tid*3+0];
    wih0l[tid*3+1] = (f16)w_ih0[tid*3+1];
    wih0l[tid*3+2] = (f16)w_ih0[tid*3+2];
  }
  { f16x2 z; z.x = (f16)0.f; z.y = (f16)0.f; hA2[tid] = z; hB2[tid] = z; }

  float cA0 = 0.f, cA1 = 0.f, cB0 = 0.f, cB1 = 0.f;
  const int r0 = s, r1 = s + 4;
  const int b0 = blk*R_ + r0, b1 = blk*R_ + r1;
  __syncthreads();

  for (int ch = 0; ch < T_/C_; ++ch) {
    // ================= phase A: layer-0 recurrence, C_ steps =================
    stage_W(W2, w_hh0, tid);
    __syncthreads();
    for (int st = 0; st < C_; ++st) {
      const int t = ch*C_ + st;
      float a0[4], a1[4];
      {
        const float x00 = x[(b0*T_ + t)*3 + 0];
        const float x01 = x[(b0*T_ + t)*3 + 1];
        const float x02 = x[(b0*T_ + t)*3 + 2];
        const float x10 = x[(b1*T_ + t)*3 + 0];
        const float x11 = x[(b1*T_ + t)*3 + 1];
        const float x12 = x[(b1*T_ + t)*3 + 2];
        #pragma unroll
        for (int k = 0; k < 4; ++k) {
          const int g = k*H_ + j;
          const float wi0 = (float)wih0l[g*3+0];
          const float wi1 = (float)wih0l[g*3+1];
          const float wi2 = (float)wih0l[g*3+2];
          const float bb  = bias0[g];
          a0[k] = bb + x00*wi0 + x01*wi1 + x02*wi2;
          a1[k] = bb + x10*wi0 + x11*wi1 + x12*wi2;
        }
      }
      #pragma unroll 8
      for (int p = 0; p < H_/2; ++p) {
        const f16x2 hv0 = hA2[r0*64 + p];
        const f16x2 hv1 = hA2[r1*64 + p];
        #pragma unroll
        for (int k = 0; k < 4; ++k) {
          const f16x2 wv = W2[(k*H_ + j)*WROW + p];
          a0[k] = fdot2_(wv, hv0, a0[k]);
          a1[k] = fdot2_(wv, hv1, a1[k]);
        }
      }
      const float i0 = sig_(a0[0]), f0 = sig_(a0[1]), g0 = tanh_(a0[2]), o0 = sig_(a0[3]);
      const float i1 = sig_(a1[0]), f1 = sig_(a1[1]), g1 = tanh_(a1[2]), o1 = sig_(a1[3]);
      cA0 = f0*cA0 + i0*g0;
      cA1 = f1*cA1 + i1*g1;
      const float h0n = o0*tanh_(cA0);
      const float h1n = o1*tanh_(cA1);
      __syncthreads();   // all reads of hA done
      hA[r0*H_ + j] = (f16)h0n;
      hA[r1*H_ + j] = (f16)h1n;
      h1c[(st*R_ + r0)*H_ + j] = (f16)h0n;
      h1c[(st*R_ + r1)*H_ + j] = (f16)h1n;
      __syncthreads();   // writes visible for next step
    }
    // ================= phase B: layer-1 input projection ====================
    stage_W(W2, w_ih1, tid);
    __syncthreads();
    {
      const int g = tid;
      const float bp = biasP[g];
      for (int st = 0; st < C_; ++st) {
        float acc[R_];
        #pragma unroll
        for (int r = 0; r < R_; ++r) acc[r] = bp;
        #pragma unroll 4
        for (int p = 0; p < H_/2; ++p) {
          const f16x2 wv = W2[g*WROW + p];
          #pragma unroll
          for (int r = 0; r < R_; ++r)
            acc[r] = fdot2_(wv, h1c2[(st*R_ + r)*64 + p], acc[r]);
        }
        #pragma unroll
        for (int r = 0; r < R_; ++r)
          xp[(st*R_ + r)*G_ + g] = acc[r];
      }
    }
    __syncthreads();
    // ================= phase C: layer-1 recurrence ==========================
    stage_W(W2, w_hh1, tid);
    __syncthreads();
    for (int st = 0; st < C_; ++st) {
      float a0[4], a1[4];
      #pragma unroll
      for (int k = 0; k < 4; ++k) {
        a0[k] = xp[(st*R_ + r0)*G_ + k*H_ + j];
        a1[k] = xp[(st*R_ + r1)*G_ + k*H_ + j];
      }
      #pragma unroll 8
      for (int p = 0; p < H_/2; ++p) {
        const f16x2 hv0 = hB2[r0*64 + p];
        const f16x2 hv1 = hB2[r1*64 + p];
        #pragma unroll
        for (int k = 0; k < 4; ++k) {
          const f16x2 wv = W2[(k*H_ + j)*WROW + p];
          a0[k] = fdot2_(wv, hv0, a0[k]);
          a1[k] = fdot2_(wv, hv1, a1[k]);
        }
      }
      const float i0 = sig_(a0[0]), f0 = sig_(a0[1]), g0 = tanh_(a0[2]), o0 = sig_(a0[3]);
      const float i1 = sig_(a1[0]), f1 = sig_(a1[1]), g1 = tanh_(a1[2]), o1 = sig_(a1[3]);
      cB0 = f0*cB0 + i0*g0;
      cB1 = f1*cB1 + i1*g1;
      const float h0n = o0*tanh_(cB0);
      const float h1n = o1*tanh_(cB1);
      __syncthreads();
      hB[r0*H_ + j] = (f16)h0n;
      hB[r1*H_ + j] = (f16)h1n;
      __syncthreads();
    }
  }
  // ================= FC head on final hB ====================================
  if (tid < R_*2) {
    const int r = tid >> 1, o = tid & 1;
    float acc = fc_b[o];
    #pragma unroll 4
    for (int d = 0; d < H_; ++d)
      acc += (float)hB[r*H_ + d] * fc_w[o*H_ + d];
    out[(blk*R_ + r)*2 + o] = acc;
  }
}

extern "C" void kernel_launch(void* const* d_in, const int* in_sizes, int n_in,
                              void* d_out, int out_size, void* d_ws, size_t ws_size,
                              hipStream_t stream) {
  const float* x     = (const float*)d_in[0];
  const float* w_ih0 = (const float*)d_in[1];
  const float* w_hh0 = (const float*)d_in[2];
  const float* b_ih0 = (const float*)d_in[3];
  const float* b_hh0 = (const float*)d_in[4];
  const float* w_ih1 = (const float*)d_in[5];
  const float* w_hh1 = (const float*)d_in[6];
  const float* b_ih1 = (const float*)d_in[7];
  const float* b_hh1 = (const float*)d_in[8];
  const float* fc_w  = (const float*)d_in[9];
  const float* fc_b  = (const float*)d_in[10];

  (void)in_sizes; (void)n_in; (void)out_size; (void)ws_size;

  hipFuncSetAttribute((const void*)lstm_fused,
                      hipFuncAttributeMaxDynamicSharedMemorySize, LDS_BYTES);

  lstm_fused<<<B_/R_, NTHR, LDS_BYTES, stream>>>(
      x, w_ih0, w_hh0, b_ih0, b_hh0, w_ih1, w_hh1, b_ih1, b_hh1,
      fc_w, fc_b, (float*)d_out, (float*)d_ws);
}

// Round 2
// 1426.196 us; speedup vs baseline: 5.8715x; 5.8715x over previous
//
#include <hip/hip_runtime.h>

// ---- problem constants ----
#define B_   2048
#define T_   512
#define H_   128
#define G_   512
#define R_   8      // real batch rows per block (M-tile = 16, rows 8..15 dead)
#define C_   8      // time-chunk steps
#define NTHR 512    // 8 waves

typedef _Float16 f16;
typedef _Float16 f16x8 __attribute__((ext_vector_type(8)));
typedef float    f32x4 __attribute__((ext_vector_type(4)));

// ---- LDS layout (bytes). Row stride 256 B, XOR-swizzle byte^=((row&7)<<4) ----
#define OFF_W1   0                      // w_ih1 f16 [512][128]       131072
#define OFF_H1C  131072                 // layer-1 inputs, 64 tokens   16384
#define OFF_HA   147456                 // layer-0 h tile [16][128]     4096
#define OFF_HB   151552                 // layer-1 h tile [16][128]     4096
#define OFF_XL   155648                 // x chunk [8][8][3] f32        1024
#define LDS_BYTES 156672

__device__ __forceinline__ float rcp_(float v) {
#if __has_builtin(__builtin_amdgcn_rcpf)
  return __builtin_amdgcn_rcpf(v);
#else
  return 1.0f / v;
#endif
}
__device__ __forceinline__ float sig_(float v)  {            // 1/(1+e^-v)
  return rcp_(1.0f + __expf(-v));
}
__device__ __forceinline__ float tanh_(float v) {            // 1 - 2/(e^2v+1)
  return 1.0f - 2.0f * rcp_(__expf(2.0f * v) + 1.0f);
}

__device__ __forceinline__ f16x8 cvt8(const float* __restrict__ p) {
  float4 a = ((const float4*)p)[0];
  float4 b = ((const float4*)p)[1];
  f16x8 v;
  v[0]=(f16)a.x; v[1]=(f16)a.y; v[2]=(f16)a.z; v[3]=(f16)a.w;
  v[4]=(f16)b.x; v[5]=(f16)b.y; v[6]=(f16)b.z; v[7]=(f16)b.w;
  return v;
}

__device__ __forceinline__ f32x4 mfma16(f16x8 a, f16x8 b, f32x4 c) {
  return __builtin_amdgcn_mfma_f32_16x16x32_f16(a, b, c, 0, 0, 0);
}

__global__ __launch_bounds__(NTHR, 2)
void lstm_mfma(const float* __restrict__ x,
               const float* __restrict__ w_ih0, const float* __restrict__ w_hh0,
               const float* __restrict__ b_ih0, const float* __restrict__ b_hh0,
               const float* __restrict__ w_ih1, const float* __restrict__ w_hh1,
               const float* __restrict__ b_ih1, const float* __restrict__ b_hh1,
               const float* __restrict__ fc_w,  const float* __restrict__ fc_b,
               float* __restrict__ out)
{
  extern __shared__ char lds[];
  char* w1L = lds + OFF_W1;
  char* h1c = lds + OFF_H1C;
  char* hA  = lds + OFF_HA;
  char* hB  = lds + OFF_HB;
  float* xL = (float*)(lds + OFF_XL);

  const int tid  = (int)threadIdx.x;
  const int lane = tid & 63;
  const int wv   = tid >> 6;          // wave 0..7 -> owns units [wv*16, wv*16+16)
  const int n    = lane & 15;
  const int hi   = lane >> 4;
  const int u0   = wv * 16;
  const int blk  = (int)blockIdx.x;
  const int rsw  = (n & 7) << 4;      // row-XOR swizzle for all frag reads

  // ---- stage w_ih1 -> LDS f16, swizzled ----
  for (int idx = tid; idx < G_*16; idx += NTHR) {
    const int g = idx >> 4, s7 = idx & 15;
    f16x8 v = cvt8(w_ih1 + g*H_ + s7*8);
    *(f16x8*)(w1L + g*256 + ((s7*16) ^ ((g&7)<<4))) = v;
  }
  // zero h tiles (dead rows 8..15 must stay 0; real rows start at 0)
  ((unsigned*)hA)[tid] = 0u; ((unsigned*)hA)[tid+512] = 0u;
  ((unsigned*)hB)[tid] = 0u; ((unsigned*)hB)[tid+512] = 0u;

  // ---- resident W_hh fragments: 128 VGPRs ----
  f16x8 whh0[4][4], whh1[4][4];
  #pragma unroll
  for (int q = 0; q < 4; ++q) {
    #pragma unroll
    for (int kc = 0; kc < 4; ++kc) {
      const int row = q*H_ + u0 + n;
      const int off = row*H_ + kc*32 + hi*8;
      whh0[q][kc] = cvt8(w_hh0 + off);
      whh1[q][kc] = cvt8(w_hh1 + off);
    }
  }
  // per-lane constants: layer-0 input weights (I=3) + fused biases
  float w0d[4][3], b0[4], bP[4];
  #pragma unroll
  for (int q = 0; q < 4; ++q) {
    const int g = q*H_ + u0 + n;
    w0d[q][0] = w_ih0[g*3+0]; w0d[q][1] = w_ih0[g*3+1]; w0d[q][2] = w_ih0[g*3+2];
    b0[q] = b_ih0[g] + b_hh0[g];
    bP[q] = b_ih1[g] + b_hh1[g];
  }
  f32x4 cA; cA[0]=0.f; cA[1]=0.f; cA[2]=0.f; cA[3]=0.f;
  f32x4 cB = cA;
  const bool updater = (lane < 32);   // lanes 0..31 own the 8 real rows
  const int  jcol    = u0 + n;
  __syncthreads();

  for (int ch = 0; ch < T_/C_; ++ch) {
    // stage x chunk: 8 steps x 8 rows x 3
    if (tid < C_*R_*3) {
      const int st = tid/24, rem = tid%24, r = rem/3, d = rem%3;
      xL[(st*R_ + r)*3 + d] = x[((size_t)(blk*R_ + r)*T_ + ch*C_ + st)*3 + d];
    }
    __syncthreads();

    // ================= phase A: layer-0 recurrence =================
    for (int st = 0; st < C_; ++st) {
      f16x8 af[4];
      #pragma unroll
      for (int kc = 0; kc < 4; ++kc)
        af[kc] = *(const f16x8*)(hA + n*256 + ((kc*64 + hi*16) ^ rsw));
      // acc init: bias + x-projection (I=3)
      float xr0[4], xr1[4], xr2[4];
      #pragma unroll
      for (int r = 0; r < 4; ++r) {
        const int row = (hi*4 + r) & 7;
        const float* xp = xL + (st*R_ + row)*3;
        xr0[r] = xp[0]; xr1[r] = xp[1]; xr2[r] = xp[2];
      }
      f32x4 acc[4];
      #pragma unroll
      for (int q = 0; q < 4; ++q)
        #pragma unroll
        for (int r = 0; r < 4; ++r)
          acc[q][r] = b0[q] + xr0[r]*w0d[q][0] + xr1[r]*w0d[q][1] + xr2[r]*w0d[q][2];
      __syncthreads();                      // all hA reads complete
      #pragma unroll
      for (int q = 0; q < 4; ++q)
        #pragma unroll
        for (int kc = 0; kc < 4; ++kc)
          acc[q] = mfma16(af[kc], whh0[q][kc], acc[q]);
      if (updater) {
        #pragma unroll
        for (int r = 0; r < 4; ++r) {
          const float iv = sig_(acc[0][r]), fv = sig_(acc[1][r]);
          const float gv = tanh_(acc[2][r]), ov = sig_(acc[3][r]);
          cA[r] = fv*cA[r] + iv*gv;
          const float h = ov * tanh_(cA[r]);
          const int row = hi*4 + r;
          const f16 hf = (f16)h;
          *(f16*)(hA  + row*256            + ((2*jcol) ^ ((row&7)<<4))) = hf;
          const int tok = st*R_ + row;
          *(f16*)(h1c + tok*256            + ((2*jcol) ^ ((row&7)<<4))) = hf;
        }
      }
      __syncthreads();                      // writes visible
    }

    // ======== phase B/C interleaved: layer-1 inproj (MFMA) + recurrence ========
    for (int m = 0; m < 4; ++m) {
      // B: x_proj1 for 16 tokens (2 steps), acc init = bias
      f32x4 axp[4];
      #pragma unroll
      for (int q = 0; q < 4; ++q) { axp[q][0]=bP[q]; axp[q][1]=bP[q]; axp[q][2]=bP[q]; axp[q][3]=bP[q]; }
      #pragma unroll
      for (int kc = 0; kc < 4; ++kc) {
        const f16x8 a1 = *(const f16x8*)(h1c + (m*16 + n)*256 + ((kc*64 + hi*16) ^ rsw));
        #pragma unroll
        for (int q = 0; q < 4; ++q) {
          const f16x8 bf = *(const f16x8*)(w1L + (q*H_ + u0 + n)*256 + ((kc*64 + hi*16) ^ rsw));
          axp[q] = mfma16(a1, bf, axp[q]);
        }
      }
      #pragma unroll
      for (int sub = 0; sub < 2; ++sub) {
        // C-in: even step -> rows 0..7 already in lanes<32; odd -> swap halves
        f32x4 acc[4];
        if (sub == 0) {
          #pragma unroll
          for (int q = 0; q < 4; ++q) acc[q] = axp[q];
        } else {
          #pragma unroll
          for (int q = 0; q < 4; ++q)
            #pragma unroll
            for (int r = 0; r < 4; ++r)
              acc[q][r] = __shfl_xor(axp[q][r], 32);
        }
        f16x8 ab[4];
        #pragma unroll
        for (int kc = 0; kc < 4; ++kc)
          ab[kc] = *(const f16x8*)(hB + n*256 + ((kc*64 + hi*16) ^ rsw));
        __syncthreads();                    // all hB reads complete
        #pragma unroll
        for (int q = 0; q < 4; ++q)
          #pragma unroll
          for (int kc = 0; kc < 4; ++kc)
            acc[q] = mfma16(ab[kc], whh1[q][kc], acc[q]);
        if (updater) {
          #pragma unroll
          for (int r = 0; r < 4; ++r) {
            const float iv = sig_(acc[0][r]), fv = sig_(acc[1][r]);
            const float gv = tanh_(acc[2][r]), ov = sig_(acc[3][r]);
            cB[r] = fv*cB[r] + iv*gv;
            const float h = ov * tanh_(cB[r]);
            const int row = hi*4 + r;
            *(f16*)(hB + row*256 + ((2*jcol) ^ ((row&7)<<4))) = (f16)h;
          }
        }
        __syncthreads();
      }
    }
  }

  // ================= FC head on final hB =================
  if (tid < R_*2) {
    const int r = tid >> 1, o = tid & 1;
    float acc = fc_b[o];
    #pragma unroll 4
    for (int d = 0; d < H_; ++d) {
      const f16 hv = *(const f16*)(hB + r*256 + ((2*d) ^ ((r&7)<<4)));
      acc += (float)hv * fc_w[o*H_ + d];
    }
    out[(blk*R_ + r)*2 + o] = acc;
  }
}

extern "C" void kernel_launch(void* const* d_in, const int* in_sizes, int n_in,
                              void* d_out, int out_size, void* d_ws, size_t ws_size,
                              hipStream_t stream) {
  const float* x     = (const float*)d_in[0];
  const float* w_ih0 = (const float*)d_in[1];
  const float* w_hh0 = (const float*)d_in[2];
  const float* b_ih0 = (const float*)d_in[3];
  const float* b_hh0 = (const float*)d_in[4];
  const float* w_ih1 = (const float*)d_in[5];
  const float* w_hh1 = (const float*)d_in[6];
  const float* b_ih1 = (const float*)d_in[7];
  const float* b_hh1 = (const float*)d_in[8];
  const float* fc_w  = (const float*)d_in[9];
  const float* fc_b  = (const float*)d_in[10];
  (void)in_sizes; (void)n_in; (void)out_size; (void)d_ws; (void)ws_size;

  hipFuncSetAttribute((const void*)lstm_mfma,
                      hipFuncAttributeMaxDynamicSharedMemorySize, LDS_BYTES);

  lstm_mfma<<<B_/R_, NTHR, LDS_BYTES, stream>>>(
      x, w_ih0, w_hh0, b_ih0, b_hh0, w_ih1, w_hh1, b_ih1, b_hh1,
      fc_w, fc_b, (float*)d_out);
}